// Round 13
// baseline (178.658 us; speedup 1.0000x reference)
//
#include <hip/hip_runtime.h>

// ANI AEV: radial + angular symmetry functions, per-atom sums.
// out: [N, 224] f32, cols 0..63 radial (sp*16+k), 64..223 angular (pair*16+ii*4+j)
//
// Pipeline (4 dispatches, no memsets):
//   prep(eaq pack, 2B/entry -> 2.4MB L2-resident table) -> scat(block-local
//   counting sort by atom-bin, SINGLE LDS atomic per record via fixed-stride
//   staging + overflow FIFO, coalesced region writes, transposed offset
//   tables) -> acc_rad -> acc_ang.
// acc kernels: coalesced offset reads, register-cached single record gather,
// 4-records-in-flight compute with shfl_xor butterfly reduction, HW v_sin/v_cos.
// eaq ushort {qd:8|qsw:6<<8|sp:2<<14}; angular record uint2 {qt|qd12<<16,
// qf1|rowpair<<16}; radial u32 {qd:12|qsw:12|sp:2|row:6}. Quant err << 0.103.

constexpr int kOutCols  = 224;
constexpr int kAngBase  = 64;
constexpr int kABUCK    = 64;     // atoms per bin
constexpr int kMaxBins  = 640;    // supports N <= 40960
constexpr int kSCap     = 4096;   // scatter block chunk cap (records)
constexpr int kNBR      = 640;    // radial scatter blocks
constexpr int kNBA      = 1024;   // angular scatter blocks
constexpr int kRCap     = 4608;   // radial recbuf cap/bin
constexpr int kACap     = 7168;   // angular recbuf cap/bin
constexpr int kRC       = 12;     // register record cache depth
constexpr int kCapR     = 16;     // radial fixed-stride staging slots/bin
constexpr int kCapA     = 12;     // angular fixed-stride staging slots/bin
constexpr int kOvf      = 512;    // overflow FIFO entries

__device__ __constant__ int c_triu[16] = {0,1,2,3, 1,4,5,6, 2,5,7,8, 3,6,8,9};
__device__ __constant__ float c_ca[4] = {0.92387953f, 0.38268343f, -0.38268343f, -0.92387953f};
__device__ __constant__ float c_sa[4] = {0.38268343f, 0.92387953f,  0.92387953f,  0.38268343f};
__device__ __constant__ float c_sh[4] = {-2.2627417f, -4.1719303f, -6.0811183f, -7.9903066f};

// quant/dequant constants
constexpr float kThQ  = 20860.437f;     // 65535/pi
constexpr float kRevD = 7.6295109e-6f;  // 0.5/65535 (theta -> revolutions)
constexpr float kD12B = 2.2627417f;     // 1.6*sqrt2
constexpr float kD12S = 1.4974026e-2f;  // 2.7*sqrt2/255
constexpr float kF1D  = 1.1732081e-13f; // 2^-31 / 3969
constexpr float kRdS  = 930.6818f;      // 4095/4.4
constexpr float kRdD  = 1.0744811e-3f;  // 4.4/4095
constexpr float kRswD = 6.1050061e-5f;  // 0.25/4095

// shfl-based exclusive scan over 1024 slots (2 barriers). wsum: shared int[16].
__device__ __forceinline__ int scan1024_exc(int cv, int tid, int* wsum, int* total)
{
    int lane = tid & 63, wv = tid >> 6;
    int x = cv;
    #pragma unroll
    for (int o = 1; o < 64; o <<= 1) {
        int t = __shfl_up(x, o, 64);
        if (lane >= o) x += t;
    }
    if (lane == 63) wsum[wv] = x;
    __syncthreads();
    if (wv == 0 && lane < 16) {
        int s = wsum[lane];
        #pragma unroll
        for (int o = 1; o < 16; o <<= 1) {
            int t = __shfl_up(s, o, 64);
            if (lane >= o) s += t;
        }
        wsum[lane] = s;
    }
    __syncthreads();
    int base = (wv == 0) ? 0 : wsum[wv - 1];
    *total = wsum[15];
    return base + x - cv;
}

// ---------------- prep: eaq pack {qd:8 | qsw:6<<8 | sp:2<<14} -------------
__global__ void prep(const float* __restrict__ ang_d, const float* __restrict__ ang_sw,
                     const int* __restrict__ aed, const int* __restrict__ species,
                     unsigned short* __restrict__ eaq, int EA)
{
    int i = blockIdx.x * blockDim.x + threadIdx.x;
    if (i >= EA) return;
    float dq = fmaxf(ang_d[i] - 0.8f, 0.0f) * (255.0f / 2.7f);
    unsigned qd = min((unsigned)(dq + 0.5f), 255u);
    unsigned qs = min((unsigned)(fmaxf(ang_sw[i], 0.0f) * 63.0f + 0.5f), 63u);
    unsigned sp = (unsigned)species[aed[i]];
    eaq[i] = (unsigned short)(qd | (qs << 8) | (sp << 14));
}

// ---------------- scat: single-atomic fixed-stride counting sort ----------
// Offset tables written TRANSPOSED: off[bin][block] (table is L2-resident).
__global__ __launch_bounds__(1024)
void scat(const float* __restrict__ rd, const float* __restrict__ rsw,
          const int* __restrict__ esrc, const int* __restrict__ edst,
          const int* __restrict__ species,
          unsigned* __restrict__ rrec, int* __restrict__ offRT, int ER, int chR,
          const float* __restrict__ angles, const int* __restrict__ cat,
          const int* __restrict__ asrc, const int* __restrict__ adst,
          const unsigned short* __restrict__ eaq,
          uint2* __restrict__ arec, int* __restrict__ offAT, int P, int chA)
{
    __shared__ uint2 sbuf[kMaxBins * kCapA];       // 61.4KB; radial aliases 640*16 u32
    __shared__ int cur[kMaxBins], off[kMaxBins + 1];
    __shared__ int wsum[16];
    __shared__ int ovfn;
    __shared__ uint4 ovfb[kOvf];                   // 8KB overflow FIFO
    int tid = threadIdx.x;

    if (blockIdx.x < kNBR) {
        // ---- radial: 4B records ----
        unsigned* stage = (unsigned*)sbuf;
        for (int t = tid; t < kMaxBins; t += 1024) cur[t] = t * kCapR;
        if (tid == 0) ovfn = 0;
        __syncthreads();
        int sb  = blockIdx.x;
        int beg = sb * chR, end = min(beg + chR, ER);
        int i0 = beg + tid * 4;
        if (i0 < end) {                            // chunk multiple of 4 -> full quad
            float4 d4 = *reinterpret_cast<const float4*>(rd + i0);
            float4 s4 = *reinterpret_cast<const float4*>(rsw + i0);
            int4   e4 = *reinterpret_cast<const int4*>(esrc + i0);
            int4   t4 = *reinterpret_cast<const int4*>(edst + i0);
            unsigned sa = (unsigned)species[t4.x], sb2 = (unsigned)species[t4.y];
            unsigned sc2 = (unsigned)species[t4.z], sd = (unsigned)species[t4.w];
            auto bld = [](float d, float s, int e, unsigned sp, unsigned& v, int& k) {
                unsigned qd = min((unsigned)(fmaxf(d - 0.8f, 0.0f) * kRdS + 0.5f), 4095u);
                unsigned qs = min((unsigned)(fmaxf(s, 0.0f) * 4095.0f + 0.5f), 4095u);
                v = qd | (qs << 12) | (sp << 24) | ((unsigned)(e & 63) << 26);
                k = e >> 6;
            };
            unsigned v0, v1, v2, v3; int k0, k1, k2, k3;
            bld(d4.x, s4.x, e4.x, sa,  v0, k0);
            bld(d4.y, s4.y, e4.y, sb2, v1, k1);
            bld(d4.z, s4.z, e4.z, sc2, v2, k2);
            bld(d4.w, s4.w, e4.w, sd,  v3, k3);
            auto ins = [&](int k, unsigned v) {
                int pos = atomicAdd(&cur[k], 1);
                int loc = pos - k * kCapR;
                if (loc < kCapR) stage[pos] = v;
                else {
                    int o = atomicAdd(&ovfn, 1);
                    if (o < kOvf) { ovfb[o].x = (unsigned)k; ovfb[o].y = (unsigned)loc; ovfb[o].z = v; }
                }
            };
            ins(k0, v0); ins(k1, v1); ins(k2, v2); ins(k3, v3);
        }
        __syncthreads();
        int cv = (tid < kMaxBins) ? (cur[tid] - tid * kCapR) : 0;
        int tot;
        int exc = scan1024_exc(cv, tid, wsum, &tot);
        if (tid < kMaxBins) off[tid] = exc;
        if (tid == 0) off[kMaxBins] = tot;
        if (tid < kMaxBins) cur[tid] = min(cv, kCapR);     // clamped count (own slot)
        __syncthreads();
        for (int s = tid; s < kMaxBins * kCapR; s += 1024) {
            int bin = s >> 4, loc = s & (kCapR - 1);
            if (loc < cur[bin]) rrec[beg + off[bin] + loc] = stage[s];
        }
        int no = min(ovfn, kOvf);
        for (int o = tid; o < no; o += 1024) {
            uint4 e = ovfb[o];
            rrec[beg + off[e.x] + (int)e.y] = e.z;
        }
        for (int t = tid; t <= kMaxBins; t += 1024) offRT[t * kNBR + sb] = off[t];
    } else {
        // ---- angular: 8B records, 2B eaq gathers ----
        for (int t = tid; t < kMaxBins; t += 1024) cur[t] = t * kCapA;
        if (tid == 0) ovfn = 0;
        __syncthreads();
        int sb  = blockIdx.x - kNBR;
        int beg = sb * chA, end = min(beg + chA, P);
        int i0 = beg + tid * 4;
        if (i0 < end) {
            uint4  s4 = *reinterpret_cast<const uint4*>(asrc + i0);
            uint4  d4 = *reinterpret_cast<const uint4*>(adst + i0);
            float4 t4 = *reinterpret_cast<const float4*>(angles + i0);
            int4   c4 = *reinterpret_cast<const int4*>(cat + i0);
            unsigned qa0 = eaq[s4.x], qb0 = eaq[d4.x];
            unsigned qa1 = eaq[s4.y], qb1 = eaq[d4.y];
            unsigned qa2 = eaq[s4.z], qb2 = eaq[d4.z];
            unsigned qa3 = eaq[s4.w], qb3 = eaq[d4.w];
            auto bld = [](unsigned qa, unsigned qb, float th, int atom, uint2& rv, int& key) {
                unsigned qd12 = (qa & 255u) + (qb & 255u);                  // 9 bits
                unsigned qf1  = ((qa >> 8) & 63u) * ((qb >> 8) & 63u);      // 12 bits
                int pair = c_triu[(qa >> 14) * 4 + (qb >> 14)];
                unsigned qt = min((unsigned)(fmaxf(th, 0.0f) * kThQ + 0.5f), 65535u);
                rv.x = qt | (qd12 << 16);
                rv.y = qf1 | ((unsigned)((atom & 63) * 10 + pair) << 16);
                key = atom >> 6;
            };
            uint2 r0, r1, r2, r3; int k0, k1, k2, k3;
            bld(qa0, qb0, t4.x, c4.x, r0, k0);
            bld(qa1, qb1, t4.y, c4.y, r1, k1);
            bld(qa2, qb2, t4.z, c4.z, r2, k2);
            bld(qa3, qb3, t4.w, c4.w, r3, k3);
            auto ins = [&](int k, uint2 r) {
                int pos = atomicAdd(&cur[k], 1);
                int loc = pos - k * kCapA;
                if (loc < kCapA) sbuf[pos] = r;
                else {
                    int o = atomicAdd(&ovfn, 1);
                    if (o < kOvf) { ovfb[o].x = (unsigned)k; ovfb[o].y = (unsigned)loc; ovfb[o].z = r.x; ovfb[o].w = r.y; }
                }
            };
            ins(k0, r0); ins(k1, r1); ins(k2, r2); ins(k3, r3);
        }
        __syncthreads();
        int cv = (tid < kMaxBins) ? (cur[tid] - tid * kCapA) : 0;
        int tot;
        int exc = scan1024_exc(cv, tid, wsum, &tot);
        if (tid < kMaxBins) off[tid] = exc;
        if (tid == 0) off[kMaxBins] = tot;
        if (tid < kMaxBins) cur[tid] = min(cv, kCapA);     // clamped count
        __syncthreads();
        for (int s = tid; s < kMaxBins * kCapA; s += 1024) {
            int bin = s / kCapA, loc = s - bin * kCapA;
            if (loc < cur[bin]) arec[beg + off[bin] + loc] = sbuf[s];
        }
        int no = min(ovfn, kOvf);
        for (int o = tid; o < no; o += 1024) {
            uint4 e = ovfb[o];
            uint2 r; r.x = e.z; r.y = e.w;
            arec[beg + off[e.x] + (int)e.y] = r;
        }
        for (int t = tid; t <= kMaxBins; t += 1024) offAT[t * kNBA + sb] = off[t];
    }
}

// ---------------- acc_rad: 4-records-in-flight, butterfly over q ----------
__global__ __launch_bounds__(1024)
void acc_rad(const unsigned* __restrict__ rrec, const int* __restrict__ offRT,
             int chR, float* __restrict__ out, int N)
{
    __shared__ unsigned rb[kRCap];            // 18.4KB
    __shared__ int cnt[64], off[65], cur[64];
    int b = blockIdx.x, tid = threadIdx.x;    // 1024 threads
    int gstart = 0, glen = 0;
    if (tid < kNBR) {
        int s0 = offRT[b * kNBR + tid];           // coalesced
        int s1 = offRT[(b + 1) * kNBR + tid];
        gstart = tid * chR + s0;
        glen   = s1 - s0;
    }
    unsigned rr[kRC];
    int gl = min(glen, kRC);
    #pragma unroll
    for (int q = 0; q < kRC; ++q) if (q < gl) rr[q] = rrec[gstart + q];
    if (tid < 64) cnt[tid] = 0;
    __syncthreads();
    #pragma unroll
    for (int q = 0; q < kRC; ++q) if (q < gl) atomicAdd(&cnt[(rr[q] >> 26) & 63], 1);
    for (int p = gstart + kRC; p < gstart + glen; ++p)
        atomicAdd(&cnt[(rrec[p] >> 26) & 63], 1);
    __syncthreads();
    if (tid < 64) {
        int x = cnt[tid], v = x;
        #pragma unroll
        for (int o = 1; o < 64; o <<= 1) {
            int t = __shfl_up(v, o, 64);
            if (tid >= o) v += t;
        }
        off[tid] = v - x; cur[tid] = v - x;
        if (tid == 63) off[64] = v;
    }
    __syncthreads();
    #pragma unroll
    for (int q = 0; q < kRC; ++q)
        if (q < gl) {
            int pos = atomicAdd(&cur[(rr[q] >> 26) & 63], 1);
            if (pos < kRCap) rb[pos] = rr[q];
        }
    for (int p = gstart + kRC; p < gstart + glen; ++p) {
        unsigned r = rrec[p];
        int pos = atomicAdd(&cur[(r >> 26) & 63], 1);
        if (pos < kRCap) rb[pos] = r;
    }
    __syncthreads();
    // pass3: wave per row batch; lane = (q=rec-slot, k=bin); butterfly over q
    int lane = tid & 63, wave = tid >> 6;
    int q = lane >> 4, k = lane & 15;
    float ck = fmaf(0.275f, (float)k, 0.8f);
    for (int row = wave; row < kABUCK; row += 16) {
        int s  = min(off[row], kRCap);
        int e1 = min(off[row + 1], kRCap);
        float a0 = 0, a1 = 0, a2 = 0, a3 = 0;
        for (int p = s + q; p < e1; p += 4) {
            unsigned r = rb[p];
            float d  = fmaf((float)(r & 4095u), kRdD, 0.8f);
            float sw = (float)((r >> 12) & 4095u) * kRswD;
            int sp   = (r >> 24) & 3;
            float x  = d - ck;
            float v  = sw * __expf(-16.0f * x * x);
            a0 += (sp == 0) ? v : 0.0f;
            a1 += (sp == 1) ? v : 0.0f;
            a2 += (sp == 2) ? v : 0.0f;
            a3 += (sp == 3) ? v : 0.0f;
        }
        a0 += __shfl_xor(a0, 16, 64); a0 += __shfl_xor(a0, 32, 64);
        a1 += __shfl_xor(a1, 16, 64); a1 += __shfl_xor(a1, 32, 64);
        a2 += __shfl_xor(a2, 16, 64); a2 += __shfl_xor(a2, 32, 64);
        a3 += __shfl_xor(a3, 16, 64); a3 += __shfl_xor(a3, 32, 64);
        float val = (q == 0) ? a0 : (q == 1) ? a1 : (q == 2) ? a2 : a3;
        int atom = b * kABUCK + row;
        if (atom < N) out[(size_t)atom * kOutCols + lane] = val;   // col = q*16+k = lane
    }
}

// ---------------- acc_ang: 4-records-in-flight, butterfly over q ----------
__global__ __launch_bounds__(1024)
void acc_ang(const uint2* __restrict__ arec, const int* __restrict__ offAT,
             int chA, float* __restrict__ out, int N)
{
    __shared__ uint2 ab[kACap];               // 57.3KB
    __shared__ int cnt[640], off[641], cur[640];
    __shared__ int wsum[16];
    int b = blockIdx.x, tid = threadIdx.x;    // thread t owns scatter-block t's segment
    int s0 = offAT[b * kNBA + tid];           // coalesced
    int s1 = offAT[(b + 1) * kNBA + tid];
    int gstart = tid * chA + s0;
    int glen   = s1 - s0;
    uint2 rr[kRC];
    int gl = min(glen, kRC);
    #pragma unroll
    for (int q = 0; q < kRC; ++q) if (q < gl) rr[q] = arec[gstart + q];
    for (int t = tid; t < 640; t += 1024) cnt[t] = 0;
    __syncthreads();
    #pragma unroll
    for (int q = 0; q < kRC; ++q) if (q < gl) atomicAdd(&cnt[rr[q].y >> 16], 1);
    for (int p = gstart + kRC; p < gstart + glen; ++p)
        atomicAdd(&cnt[arec[p].y >> 16], 1);
    __syncthreads();
    int cv = (tid < 640) ? cnt[tid] : 0;
    int tot;
    int exc = scan1024_exc(cv, tid, wsum, &tot);
    if (tid < 640) { off[tid] = exc; cur[tid] = exc; }
    if (tid == 0) off[640] = tot;
    __syncthreads();
    #pragma unroll
    for (int q = 0; q < kRC; ++q)
        if (q < gl) {
            int pos = atomicAdd(&cur[rr[q].y >> 16], 1);
            if (pos < kACap) ab[pos] = rr[q];
        }
    for (int p = gstart + kRC; p < gstart + glen; ++p) {
        uint2 r = arec[p];
        int pos = atomicAdd(&cur[r.y >> 16], 1);
        if (pos < kACap) ab[pos] = r;
    }
    __syncthreads();
    // pass3: 16-lane group per row; lane = (q=rec-slot, j=angle); butterfly over q
    int g = tid >> 4, lam = tid & 15;
    int q = lam >> 2, j = lam & 3;
    float caj = c_ca[j], saj = c_sa[j];
    int atom = b * kABUCK + g;
    if (atom < N) {
        float* orow = out + (size_t)atom * kOutCols + kAngBase;
        for (int pr = 0; pr < 10; ++pr) {
            int s  = min(off[g * 10 + pr], kACap);
            int e1 = min(off[g * 10 + pr + 1], kACap);
            float s0v = 0, s1v = 0, s2v = 0, s3v = 0;
            for (int p = s + q; p < e1; p += 4) {
                uint2 r = ab[p];
                float rev = (float)(r.x & 0xFFFFu) * kRevD;   // theta in revolutions
                float d12 = fmaf((float)(r.x >> 16), kD12S, kD12B);
                float f1  = (float)(r.y & 0xFFFFu) * kF1D;
                float sn, cs;
                asm("v_sin_f32 %0, %1" : "=v"(sn) : "v"(rev));
                asm("v_cos_f32 %0, %1" : "=v"(cs) : "v"(rev));
                float cj = fmaf(cs, caj, sn * saj);
                float t  = 1.0f + cj;
                float t2 = t * t, t4 = t2 * t2, t8 = t4 * t4, t16 = t8 * t8;
                float w  = f1 * (t16 * t16);
                float x0 = d12 + c_sh[0]; s0v = fmaf(w, __expf(-x0 * x0), s0v);
                float x1 = d12 + c_sh[1]; s1v = fmaf(w, __expf(-x1 * x1), s1v);
                float x2 = d12 + c_sh[2]; s2v = fmaf(w, __expf(-x2 * x2), s2v);
                float x3 = d12 + c_sh[3]; s3v = fmaf(w, __expf(-x3 * x3), s3v);
            }
            s0v += __shfl_xor(s0v, 4, 64); s0v += __shfl_xor(s0v, 8, 64);
            s1v += __shfl_xor(s1v, 4, 64); s1v += __shfl_xor(s1v, 8, 64);
            s2v += __shfl_xor(s2v, 4, 64); s2v += __shfl_xor(s2v, 8, 64);
            s3v += __shfl_xor(s3v, 4, 64); s3v += __shfl_xor(s3v, 8, 64);
            float val = (q == 0) ? s0v : (q == 1) ? s1v : (q == 2) ? s2v : s3v;
            orow[pr * 16 + lam] = val;    // col = q*4+j = lam (ii = q)
        }
    }
}

// ---------------- fallback: direct global-atomic path ----------------
__global__ void radial_kernel(const float* __restrict__ rd, const float* __restrict__ rsw,
                              const int* __restrict__ esrc, const int* __restrict__ edst,
                              const int* __restrict__ species,
                              float* __restrict__ out, int ER)
{
    int i = blockIdx.x * blockDim.x + threadIdx.x;
    if (i >= ER) return;
    float d   = rd[i];
    float sw  = 0.25f * rsw[i];
    int   src = esrc[i];
    int   sp  = species[edst[i]];
    float* base = out + (size_t)src * kOutCols + sp * 16;
    float t = (d - 0.8f) * (1.0f / 0.275f);
    int klo = max(0, (int)ceilf(t - 4.0f));
    int khi = min(15, (int)floorf(t + 4.0f));
    for (int k = klo; k <= khi; ++k) {
        float x = d - fmaf(0.275f, (float)k, 0.8f);
        float v = sw * __expf(-16.0f * x * x);
        if (v > 1e-8f) unsafeAtomicAdd(base + k, v);
    }
}

__global__ void angular_fallback(const float* __restrict__ angles, const int* __restrict__ cat,
                                 const int* __restrict__ asrc, const int* __restrict__ adst,
                                 const float* __restrict__ ang_d, const float* __restrict__ ang_sw,
                                 const int* __restrict__ aed, const int* __restrict__ species,
                                 float* __restrict__ out, int P)
{
    int i = blockIdx.x * blockDim.x + threadIdx.x;
    if (i >= P) return;
    int e1i = asrc[i], e2i = adst[i];
    float d1 = 1.41421356237f * ang_d[e1i];
    float d2 = 1.41421356237f * ang_d[e2i];
    float w1 = 2.1579187e-05f * ang_sw[e1i];
    float w2 = 2.1579187e-05f * ang_sw[e2i];
    int sp1 = species[aed[e1i]], sp2 = species[aed[e2i]];
    float d12 = d1 + d2;
    float f1  = w1 * w2;
    int pair = c_triu[sp1 * 4 + sp2];
    float* base = out + (size_t)cat[i] * kOutCols + kAngBase + pair * 16;

    float s, c;
    __sincosf(angles[i], &s, &c);
    const float ca0 = 0.92387953f, sa0 = 0.38268343f;
    float cth[4];
    cth[0] = fmaf(c,  ca0, s * sa0);
    cth[1] = fmaf(c,  sa0, s * ca0);
    cth[2] = fmaf(c, -sa0, s * ca0);
    cth[3] = fmaf(c, -ca0, s * sa0);
    float fac1[4];
    #pragma unroll
    for (int j = 0; j < 4; ++j) {
        float t  = 1.0f + cth[j];
        float t2 = t * t, t4 = t2 * t2, t8 = t4 * t4, t16 = t8 * t8;
        fac1[j]  = f1 * (t16 * t16);
    }
    const float shiftA[4] = {-2.2627417f, -4.1719303f, -6.0811183f, -7.9903066f};
    #pragma unroll
    for (int ii = 0; ii < 4; ++ii) {
        float x  = d12 + shiftA[ii];
        float f2 = __expf(-x * x);
        if (f2 < 1e-7f) continue;
        #pragma unroll
        for (int j = 0; j < 4; ++j) {
            float v = f2 * fac1[j];
            if (v > 1e-8f) unsafeAtomicAdd(base + ii * 4 + j, v);
        }
    }
}

extern "C" void kernel_launch(void* const* d_in, const int* in_sizes, int n_in,
                              void* d_out, int out_size, void* d_ws, size_t ws_size,
                              hipStream_t stream)
{
    const int*   species = (const int*)  d_in[0];
    const float* rad_d   = (const float*)d_in[1];
    const float* rad_sw  = (const float*)d_in[2];
    const int*   esrc    = (const int*)  d_in[3];
    const int*   edst    = (const int*)  d_in[4];
    const float* ang_d   = (const float*)d_in[5];
    const float* ang_sw  = (const float*)d_in[6];
    const float* angles  = (const float*)d_in[7];
    const int*   cat     = (const int*)  d_in[8];
    const int*   asrc    = (const int*)  d_in[9];
    const int*   adst    = (const int*)  d_in[10];
    const int*   aed     = (const int*)  d_in[11];
    float* out = (float*)d_out;

    const int N  = in_sizes[0];
    const int ER = in_sizes[1];
    const int EA = in_sizes[5];
    const int P  = in_sizes[7];

    const int NB  = (N + kABUCK - 1) / kABUCK;                 // atom bins
    const int chR = (((ER + kNBR - 1) / kNBR) + 3) & ~3;       // mult-of-4 chunk
    const int chA = (((P  + kNBA - 1) / kNBA) + 3) & ~3;

    // workspace layout
    char* w = (char*)d_ws;
    size_t pos = 0;
    auto take = [&](size_t nbytes) {
        size_t cur = pos;
        pos = (pos + nbytes + 255) & ~(size_t)255;
        return cur;
    };
    size_t ea_o   = take((size_t)EA * 2);                          // packed eaq (ushort)
    size_t rrec_o = take((size_t)kNBR * chR * 4);
    size_t arec_o = take((size_t)kNBA * chA * 8);
    size_t ort_o  = take((size_t)(kMaxBins + 1) * kNBR * 4);       // transposed
    size_t oat_o  = take((size_t)(kMaxBins + 1) * kNBA * 4);       // transposed
    const size_t need = pos;

    const bool sorted_ok = (ws_size >= need) && (NB <= kMaxBins) &&
                           (chR <= kSCap) && (chA <= kSCap) &&
                           ((P & 3) == 0) && ((ER & 3) == 0);

    if (sorted_ok) {
        unsigned short* eaq = (unsigned short*)(w + ea_o);
        unsigned* rrec  = (unsigned*)(w + rrec_o);
        uint2*    arec  = (uint2*)(w + arec_o);
        int*      offRT = (int*)(w + ort_o);
        int*      offAT = (int*)(w + oat_o);

        prep<<<(EA + 255) / 256, 256, 0, stream>>>(ang_d, ang_sw, aed, species, eaq, EA);
        scat<<<kNBR + kNBA, 1024, 0, stream>>>(rad_d, rad_sw, esrc, edst, species,
                                               rrec, offRT, ER, chR,
                                               angles, cat, asrc, adst, eaq,
                                               arec, offAT, P, chA);
        acc_rad<<<NB, 1024, 0, stream>>>(rrec, offRT, chR, out, N);
        acc_ang<<<NB, 1024, 0, stream>>>(arec, offAT, chA, out, N);
    } else {
        hipMemsetAsync(d_out, 0, (size_t)out_size * sizeof(float), stream);
        radial_kernel<<<(ER + 255) / 256, 256, 0, stream>>>(rad_d, rad_sw, esrc, edst, species, out, ER);
        angular_fallback<<<(P + 255) / 256, 256, 0, stream>>>(angles, cat, asrc, adst,
                                                              ang_d, ang_sw, aed, species, out, P);
    }
}

// Round 14
// 172.679 us; speedup vs baseline: 1.0346x; 1.0346x over previous
//
#include <hip/hip_runtime.h>

// ANI AEV: radial + angular symmetry functions, per-atom sums.
// out: [N, 224] f32, cols 0..63 radial (sp*16+k), 64..223 angular (pair*16+ii*4+j)
//
// Pipeline (3 dispatches, dependency-graph packed for overlap):
//   D1 fused1 = scat_rad || prep      (independent; stream hides under gathers)
//   D2 fused2 = scat_ang || acc_rad   (acc_rad needs only D1; VALU work hides
//                                      under scat_ang's 8M random eaq gathers)
//   D3 acc_ang
// scat: block-local counting sort by atom-bin, single LDS atomic per record
// (fixed-stride staging + overflow FIFO), coalesced region writes, transposed
// offset tables. acc: coalesced offset reads, register-cached record gather,
// 4-records-in-flight compute + shfl_xor butterfly, HW v_sin/v_cos.
// eaq ushort {qd:8|qsw:6<<8|sp:2<<14}; angular record uint2 {qt|qd12<<16,
// qf1|rowpair<<16}; radial u32 {qd:12|qsw:12|sp:2|row:6}. Quant err << 0.103.

constexpr int kOutCols  = 224;
constexpr int kAngBase  = 64;
constexpr int kABUCK    = 64;     // atoms per bin
constexpr int kMaxBins  = 640;    // supports N <= 40960
constexpr int kSCap     = 4096;   // scatter block chunk cap (records)
constexpr int kNBR      = 640;    // radial scatter blocks
constexpr int kNBA      = 1024;   // angular scatter blocks
constexpr int kRCap     = 4608;   // radial recbuf cap/bin
constexpr int kACap     = 7168;   // angular recbuf cap/bin
constexpr int kRC       = 12;     // register record cache depth
constexpr int kCapR     = 16;     // radial fixed-stride staging slots/bin
constexpr int kCapA     = 12;     // angular fixed-stride staging slots/bin
constexpr int kOvf      = 512;    // overflow FIFO entries

__device__ __constant__ int c_triu[16] = {0,1,2,3, 1,4,5,6, 2,5,7,8, 3,6,8,9};
__device__ __constant__ float c_ca[4] = {0.92387953f, 0.38268343f, -0.38268343f, -0.92387953f};
__device__ __constant__ float c_sa[4] = {0.38268343f, 0.92387953f,  0.92387953f,  0.38268343f};
__device__ __constant__ float c_sh[4] = {-2.2627417f, -4.1719303f, -6.0811183f, -7.9903066f};

// quant/dequant constants
constexpr float kThQ  = 20860.437f;     // 65535/pi
constexpr float kRevD = 7.6295109e-6f;  // 0.5/65535 (theta -> revolutions)
constexpr float kD12B = 2.2627417f;     // 1.6*sqrt2
constexpr float kD12S = 1.4974026e-2f;  // 2.7*sqrt2/255
constexpr float kF1D  = 1.1732081e-13f; // 2^-31 / 3969
constexpr float kRdS  = 930.6818f;      // 4095/4.4
constexpr float kRdD  = 1.0744811e-3f;  // 4.4/4095
constexpr float kRswD = 6.1050061e-5f;  // 0.25/4095

// shfl-based exclusive scan over 1024 slots (2 barriers). wsum: shared int[16].
__device__ __forceinline__ int scan1024_exc(int cv, int tid, int* wsum, int* total)
{
    int lane = tid & 63, wv = tid >> 6;
    int x = cv;
    #pragma unroll
    for (int o = 1; o < 64; o <<= 1) {
        int t = __shfl_up(x, o, 64);
        if (lane >= o) x += t;
    }
    if (lane == 63) wsum[wv] = x;
    __syncthreads();
    if (wv == 0 && lane < 16) {
        int s = wsum[lane];
        #pragma unroll
        for (int o = 1; o < 16; o <<= 1) {
            int t = __shfl_up(s, o, 64);
            if (lane >= o) s += t;
        }
        wsum[lane] = s;
    }
    __syncthreads();
    int base = (wv == 0) ? 0 : wsum[wv - 1];
    *total = wsum[15];
    return base + x - cv;
}

// ---------------- D1: scat_rad || prep ------------------------------------
__global__ __launch_bounds__(1024)
void fused1(const float* __restrict__ rd, const float* __restrict__ rsw,
            const int* __restrict__ esrc, const int* __restrict__ edst,
            const int* __restrict__ species,
            unsigned* __restrict__ rrec, int* __restrict__ offRT, int ER, int chR,
            const float* __restrict__ ang_d, const float* __restrict__ ang_sw,
            const int* __restrict__ aed, unsigned short* __restrict__ eaq, int EA)
{
    __shared__ unsigned stage[kMaxBins * kCapR];   // 40,960B
    __shared__ int cur[kMaxBins], off[kMaxBins + 1];
    __shared__ int wsum[16];
    __shared__ int ovfn;
    __shared__ uint4 ovfb[kOvf];                   // 8KB
    int tid = threadIdx.x;

    if (blockIdx.x < kNBR) {
        // ---- scat_rad: 4B records, single atomic, fixed-stride staging ----
        for (int t = tid; t < kMaxBins; t += 1024) cur[t] = t * kCapR;
        if (tid == 0) ovfn = 0;
        __syncthreads();
        int sb  = blockIdx.x;
        int beg = sb * chR, end = min(beg + chR, ER);
        int i0 = beg + tid * 4;
        if (i0 < end) {                            // chunk multiple of 4 -> full quad
            float4 d4 = *reinterpret_cast<const float4*>(rd + i0);
            float4 s4 = *reinterpret_cast<const float4*>(rsw + i0);
            int4   e4 = *reinterpret_cast<const int4*>(esrc + i0);
            int4   t4 = *reinterpret_cast<const int4*>(edst + i0);
            unsigned sa = (unsigned)species[t4.x], sb2 = (unsigned)species[t4.y];
            unsigned sc2 = (unsigned)species[t4.z], sd = (unsigned)species[t4.w];
            auto bld = [](float d, float s, int e, unsigned sp, unsigned& v, int& k) {
                unsigned qd = min((unsigned)(fmaxf(d - 0.8f, 0.0f) * kRdS + 0.5f), 4095u);
                unsigned qs = min((unsigned)(fmaxf(s, 0.0f) * 4095.0f + 0.5f), 4095u);
                v = qd | (qs << 12) | (sp << 24) | ((unsigned)(e & 63) << 26);
                k = e >> 6;
            };
            unsigned v0, v1, v2, v3; int k0, k1, k2, k3;
            bld(d4.x, s4.x, e4.x, sa,  v0, k0);
            bld(d4.y, s4.y, e4.y, sb2, v1, k1);
            bld(d4.z, s4.z, e4.z, sc2, v2, k2);
            bld(d4.w, s4.w, e4.w, sd,  v3, k3);
            auto ins = [&](int k, unsigned v) {
                int pos = atomicAdd(&cur[k], 1);
                int loc = pos - k * kCapR;
                if (loc < kCapR) stage[pos] = v;
                else {
                    int o = atomicAdd(&ovfn, 1);
                    if (o < kOvf) { ovfb[o].x = (unsigned)k; ovfb[o].y = (unsigned)loc; ovfb[o].z = v; }
                }
            };
            ins(k0, v0); ins(k1, v1); ins(k2, v2); ins(k3, v3);
        }
        __syncthreads();
        int cv = (tid < kMaxBins) ? (cur[tid] - tid * kCapR) : 0;
        int tot;
        int exc = scan1024_exc(cv, tid, wsum, &tot);
        if (tid < kMaxBins) off[tid] = exc;
        if (tid == 0) off[kMaxBins] = tot;
        if (tid < kMaxBins) cur[tid] = min(cv, kCapR);     // clamped count
        __syncthreads();
        for (int s = tid; s < kMaxBins * kCapR; s += 1024) {
            int bin = s >> 4, loc = s & (kCapR - 1);
            if (loc < cur[bin]) rrec[beg + off[bin] + loc] = stage[s];
        }
        int no = min(ovfn, kOvf);
        for (int o = tid; o < no; o += 1024) {
            uint4 e = ovfb[o];
            rrec[beg + off[e.x] + (int)e.y] = e.z;
        }
        for (int t = tid; t <= kMaxBins; t += 1024) offRT[t * kNBR + sb] = off[t];
    } else {
        // ---- prep: eaq pack {qd:8 | qsw:6<<8 | sp:2<<14} ----
        int i = (blockIdx.x - kNBR) * 1024 + tid;
        if (i < EA) {
            float dq = fmaxf(ang_d[i] - 0.8f, 0.0f) * (255.0f / 2.7f);
            unsigned qd = min((unsigned)(dq + 0.5f), 255u);
            unsigned qs = min((unsigned)(fmaxf(ang_sw[i], 0.0f) * 63.0f + 0.5f), 63u);
            unsigned sp = (unsigned)species[aed[i]];
            eaq[i] = (unsigned short)(qd | (qs << 8) | (sp << 14));
        }
    }
}

// ---------------- D2: scat_ang || acc_rad ---------------------------------
// LDS manually unioned: scat_ang needs 74.8KB, acc_rad 19KB -> one arena.
__global__ __launch_bounds__(1024)
void fused2(const float* __restrict__ angles, const int* __restrict__ cat,
            const int* __restrict__ asrc, const int* __restrict__ adst,
            const unsigned short* __restrict__ eaq,
            uint2* __restrict__ arec, int* __restrict__ offAT, int P, int chA,
            const unsigned* __restrict__ rrec, const int* __restrict__ offRT,
            int chR, float* __restrict__ out, int N)
{
    __shared__ uint4 raw[4680];                    // 74,880B arena
    int tid = threadIdx.x;

    if (blockIdx.x < kNBA) {
        // ---- scat_ang: 8B records, 2B eaq gathers ----
        uint2* sbuf = (uint2*)raw;                             // 61,440B
        int*   cur  = (int*)((char*)raw + 61440);              // 2,560B
        int*   off  = (int*)((char*)raw + 64000);              // 2,564B
        int*   wsum = (int*)((char*)raw + 66564);              // 64B
        int*   ovfn = (int*)((char*)raw + 66628);              // 4B
        uint4* ovfb = (uint4*)((char*)raw + 66640);            // 8,192B -> 74,832

        for (int t = tid; t < kMaxBins; t += 1024) cur[t] = t * kCapA;
        if (tid == 0) *ovfn = 0;
        __syncthreads();
        int sb  = blockIdx.x;
        int beg = sb * chA, end = min(beg + chA, P);
        int i0 = beg + tid * 4;
        if (i0 < end) {
            uint4  s4 = *reinterpret_cast<const uint4*>(asrc + i0);
            uint4  d4 = *reinterpret_cast<const uint4*>(adst + i0);
            float4 t4 = *reinterpret_cast<const float4*>(angles + i0);
            int4   c4 = *reinterpret_cast<const int4*>(cat + i0);
            unsigned qa0 = eaq[s4.x], qb0 = eaq[d4.x];
            unsigned qa1 = eaq[s4.y], qb1 = eaq[d4.y];
            unsigned qa2 = eaq[s4.z], qb2 = eaq[d4.z];
            unsigned qa3 = eaq[s4.w], qb3 = eaq[d4.w];
            auto bld = [](unsigned qa, unsigned qb, float th, int atom, uint2& rv, int& key) {
                unsigned qd12 = (qa & 255u) + (qb & 255u);                  // 9 bits
                unsigned qf1  = ((qa >> 8) & 63u) * ((qb >> 8) & 63u);      // 12 bits
                int pair = c_triu[(qa >> 14) * 4 + (qb >> 14)];
                unsigned qt = min((unsigned)(fmaxf(th, 0.0f) * kThQ + 0.5f), 65535u);
                rv.x = qt | (qd12 << 16);
                rv.y = qf1 | ((unsigned)((atom & 63) * 10 + pair) << 16);
                key = atom >> 6;
            };
            uint2 r0, r1, r2, r3; int k0, k1, k2, k3;
            bld(qa0, qb0, t4.x, c4.x, r0, k0);
            bld(qa1, qb1, t4.y, c4.y, r1, k1);
            bld(qa2, qb2, t4.z, c4.z, r2, k2);
            bld(qa3, qb3, t4.w, c4.w, r3, k3);
            auto ins = [&](int k, uint2 r) {
                int pos = atomicAdd(&cur[k], 1);
                int loc = pos - k * kCapA;
                if (loc < kCapA) sbuf[pos] = r;
                else {
                    int o = atomicAdd(ovfn, 1);
                    if (o < kOvf) { ovfb[o].x = (unsigned)k; ovfb[o].y = (unsigned)loc; ovfb[o].z = r.x; ovfb[o].w = r.y; }
                }
            };
            ins(k0, r0); ins(k1, r1); ins(k2, r2); ins(k3, r3);
        }
        __syncthreads();
        int cv = (tid < kMaxBins) ? (cur[tid] - tid * kCapA) : 0;
        int tot;
        int exc = scan1024_exc(cv, tid, wsum, &tot);
        if (tid < kMaxBins) off[tid] = exc;
        if (tid == 0) off[kMaxBins] = tot;
        if (tid < kMaxBins) cur[tid] = min(cv, kCapA);     // clamped count
        __syncthreads();
        for (int s = tid; s < kMaxBins * kCapA; s += 1024) {
            int bin = s / kCapA, loc = s - bin * kCapA;
            if (loc < cur[bin]) arec[beg + off[bin] + loc] = sbuf[s];
        }
        int no = min(*ovfn, kOvf);
        for (int o = tid; o < no; o += 1024) {
            uint4 e = ovfb[o];
            uint2 r; r.x = e.z; r.y = e.w;
            arec[beg + off[e.x] + (int)e.y] = r;
        }
        for (int t = tid; t <= kMaxBins; t += 1024) offAT[t * kNBA + sb] = off[t];
    } else {
        // ---- acc_rad: 4-records-in-flight, butterfly over q ----
        unsigned* rb  = (unsigned*)raw;                        // 18,432B
        int*      cnt = (int*)((char*)raw + 18432);            // 256B
        int*      off = (int*)((char*)raw + 18688);            // 260B
        int*      cur = (int*)((char*)raw + 18948);            // 256B

        int b = blockIdx.x - kNBA;
        int gstart = 0, glen = 0;
        if (tid < kNBR) {
            int s0 = offRT[b * kNBR + tid];           // coalesced
            int s1 = offRT[(b + 1) * kNBR + tid];
            gstart = tid * chR + s0;
            glen   = s1 - s0;
        }
        unsigned rr[kRC];
        int gl = min(glen, kRC);
        #pragma unroll
        for (int q = 0; q < kRC; ++q) if (q < gl) rr[q] = rrec[gstart + q];
        if (tid < 64) cnt[tid] = 0;
        __syncthreads();
        #pragma unroll
        for (int q = 0; q < kRC; ++q) if (q < gl) atomicAdd(&cnt[(rr[q] >> 26) & 63], 1);
        for (int p = gstart + kRC; p < gstart + glen; ++p)
            atomicAdd(&cnt[(rrec[p] >> 26) & 63], 1);
        __syncthreads();
        if (tid < 64) {
            int x = cnt[tid], v = x;
            #pragma unroll
            for (int o = 1; o < 64; o <<= 1) {
                int t = __shfl_up(v, o, 64);
                if (tid >= o) v += t;
            }
            off[tid] = v - x; cur[tid] = v - x;
            if (tid == 63) off[64] = v;
        }
        __syncthreads();
        #pragma unroll
        for (int q = 0; q < kRC; ++q)
            if (q < gl) {
                int pos = atomicAdd(&cur[(rr[q] >> 26) & 63], 1);
                if (pos < kRCap) rb[pos] = rr[q];
            }
        for (int p = gstart + kRC; p < gstart + glen; ++p) {
            unsigned r = rrec[p];
            int pos = atomicAdd(&cur[(r >> 26) & 63], 1);
            if (pos < kRCap) rb[pos] = r;
        }
        __syncthreads();
        int lane = tid & 63, wave = tid >> 6;
        int q = lane >> 4, k = lane & 15;
        float ck = fmaf(0.275f, (float)k, 0.8f);
        for (int row = wave; row < kABUCK; row += 16) {
            int s  = min(off[row], kRCap);
            int e1 = min(off[row + 1], kRCap);
            float a0 = 0, a1 = 0, a2 = 0, a3 = 0;
            for (int p = s + q; p < e1; p += 4) {
                unsigned r = rb[p];
                float d  = fmaf((float)(r & 4095u), kRdD, 0.8f);
                float sw = (float)((r >> 12) & 4095u) * kRswD;
                int sp   = (r >> 24) & 3;
                float x  = d - ck;
                float v  = sw * __expf(-16.0f * x * x);
                a0 += (sp == 0) ? v : 0.0f;
                a1 += (sp == 1) ? v : 0.0f;
                a2 += (sp == 2) ? v : 0.0f;
                a3 += (sp == 3) ? v : 0.0f;
            }
            a0 += __shfl_xor(a0, 16, 64); a0 += __shfl_xor(a0, 32, 64);
            a1 += __shfl_xor(a1, 16, 64); a1 += __shfl_xor(a1, 32, 64);
            a2 += __shfl_xor(a2, 16, 64); a2 += __shfl_xor(a2, 32, 64);
            a3 += __shfl_xor(a3, 16, 64); a3 += __shfl_xor(a3, 32, 64);
            float val = (q == 0) ? a0 : (q == 1) ? a1 : (q == 2) ? a2 : a3;
            int atom = b * kABUCK + row;
            if (atom < N) out[(size_t)atom * kOutCols + lane] = val;   // col = lane
        }
    }
}

// ---------------- D3: acc_ang ---------------------------------------------
__global__ __launch_bounds__(1024)
void acc_ang(const uint2* __restrict__ arec, const int* __restrict__ offAT,
             int chA, float* __restrict__ out, int N)
{
    __shared__ uint2 ab[kACap];               // 57.3KB
    __shared__ int cnt[640], off[641], cur[640];
    __shared__ int wsum[16];
    int b = blockIdx.x, tid = threadIdx.x;    // thread t owns scatter-block t's segment
    int s0 = offAT[b * kNBA + tid];           // coalesced
    int s1 = offAT[(b + 1) * kNBA + tid];
    int gstart = tid * chA + s0;
    int glen   = s1 - s0;
    uint2 rr[kRC];
    int gl = min(glen, kRC);
    #pragma unroll
    for (int q = 0; q < kRC; ++q) if (q < gl) rr[q] = arec[gstart + q];
    for (int t = tid; t < 640; t += 1024) cnt[t] = 0;
    __syncthreads();
    #pragma unroll
    for (int q = 0; q < kRC; ++q) if (q < gl) atomicAdd(&cnt[rr[q].y >> 16], 1);
    for (int p = gstart + kRC; p < gstart + glen; ++p)
        atomicAdd(&cnt[arec[p].y >> 16], 1);
    __syncthreads();
    int cv = (tid < 640) ? cnt[tid] : 0;
    int tot;
    int exc = scan1024_exc(cv, tid, wsum, &tot);
    if (tid < 640) { off[tid] = exc; cur[tid] = exc; }
    if (tid == 0) off[640] = tot;
    __syncthreads();
    #pragma unroll
    for (int q = 0; q < kRC; ++q)
        if (q < gl) {
            int pos = atomicAdd(&cur[rr[q].y >> 16], 1);
            if (pos < kACap) ab[pos] = rr[q];
        }
    for (int p = gstart + kRC; p < gstart + glen; ++p) {
        uint2 r = arec[p];
        int pos = atomicAdd(&cur[r.y >> 16], 1);
        if (pos < kACap) ab[pos] = r;
    }
    __syncthreads();
    int g = tid >> 4, lam = tid & 15;
    int q = lam >> 2, j = lam & 3;
    float caj = c_ca[j], saj = c_sa[j];
    int atom = b * kABUCK + g;
    if (atom < N) {
        float* orow = out + (size_t)atom * kOutCols + kAngBase;
        for (int pr = 0; pr < 10; ++pr) {
            int s  = min(off[g * 10 + pr], kACap);
            int e1 = min(off[g * 10 + pr + 1], kACap);
            float s0v = 0, s1v = 0, s2v = 0, s3v = 0;
            for (int p = s + q; p < e1; p += 4) {
                uint2 r = ab[p];
                float rev = (float)(r.x & 0xFFFFu) * kRevD;   // theta in revolutions
                float d12 = fmaf((float)(r.x >> 16), kD12S, kD12B);
                float f1  = (float)(r.y & 0xFFFFu) * kF1D;
                float sn, cs;
                asm("v_sin_f32 %0, %1" : "=v"(sn) : "v"(rev));
                asm("v_cos_f32 %0, %1" : "=v"(cs) : "v"(rev));
                float cj = fmaf(cs, caj, sn * saj);
                float t  = 1.0f + cj;
                float t2 = t * t, t4 = t2 * t2, t8 = t4 * t4, t16 = t8 * t8;
                float w  = f1 * (t16 * t16);
                float x0 = d12 + c_sh[0]; s0v = fmaf(w, __expf(-x0 * x0), s0v);
                float x1 = d12 + c_sh[1]; s1v = fmaf(w, __expf(-x1 * x1), s1v);
                float x2 = d12 + c_sh[2]; s2v = fmaf(w, __expf(-x2 * x2), s2v);
                float x3 = d12 + c_sh[3]; s3v = fmaf(w, __expf(-x3 * x3), s3v);
            }
            s0v += __shfl_xor(s0v, 4, 64); s0v += __shfl_xor(s0v, 8, 64);
            s1v += __shfl_xor(s1v, 4, 64); s1v += __shfl_xor(s1v, 8, 64);
            s2v += __shfl_xor(s2v, 4, 64); s2v += __shfl_xor(s2v, 8, 64);
            s3v += __shfl_xor(s3v, 4, 64); s3v += __shfl_xor(s3v, 8, 64);
            float val = (q == 0) ? s0v : (q == 1) ? s1v : (q == 2) ? s2v : s3v;
            orow[pr * 16 + lam] = val;    // col = q*4+j = lam (ii = q)
        }
    }
}

// ---------------- fallback: direct global-atomic path ----------------
__global__ void radial_kernel(const float* __restrict__ rd, const float* __restrict__ rsw,
                              const int* __restrict__ esrc, const int* __restrict__ edst,
                              const int* __restrict__ species,
                              float* __restrict__ out, int ER)
{
    int i = blockIdx.x * blockDim.x + threadIdx.x;
    if (i >= ER) return;
    float d   = rd[i];
    float sw  = 0.25f * rsw[i];
    int   src = esrc[i];
    int   sp  = species[edst[i]];
    float* base = out + (size_t)src * kOutCols + sp * 16;
    float t = (d - 0.8f) * (1.0f / 0.275f);
    int klo = max(0, (int)ceilf(t - 4.0f));
    int khi = min(15, (int)floorf(t + 4.0f));
    for (int k = klo; k <= khi; ++k) {
        float x = d - fmaf(0.275f, (float)k, 0.8f);
        float v = sw * __expf(-16.0f * x * x);
        if (v > 1e-8f) unsafeAtomicAdd(base + k, v);
    }
}

__global__ void angular_fallback(const float* __restrict__ angles, const int* __restrict__ cat,
                                 const int* __restrict__ asrc, const int* __restrict__ adst,
                                 const float* __restrict__ ang_d, const float* __restrict__ ang_sw,
                                 const int* __restrict__ aed, const int* __restrict__ species,
                                 float* __restrict__ out, int P)
{
    int i = blockIdx.x * blockDim.x + threadIdx.x;
    if (i >= P) return;
    int e1i = asrc[i], e2i = adst[i];
    float d1 = 1.41421356237f * ang_d[e1i];
    float d2 = 1.41421356237f * ang_d[e2i];
    float w1 = 2.1579187e-05f * ang_sw[e1i];
    float w2 = 2.1579187e-05f * ang_sw[e2i];
    int sp1 = species[aed[e1i]], sp2 = species[aed[e2i]];
    float d12 = d1 + d2;
    float f1  = w1 * w2;
    int pair = c_triu[sp1 * 4 + sp2];
    float* base = out + (size_t)cat[i] * kOutCols + kAngBase + pair * 16;

    float s, c;
    __sincosf(angles[i], &s, &c);
    const float ca0 = 0.92387953f, sa0 = 0.38268343f;
    float cth[4];
    cth[0] = fmaf(c,  ca0, s * sa0);
    cth[1] = fmaf(c,  sa0, s * ca0);
    cth[2] = fmaf(c, -sa0, s * ca0);
    cth[3] = fmaf(c, -ca0, s * sa0);
    float fac1[4];
    #pragma unroll
    for (int j = 0; j < 4; ++j) {
        float t  = 1.0f + cth[j];
        float t2 = t * t, t4 = t2 * t2, t8 = t4 * t4, t16 = t8 * t8;
        fac1[j]  = f1 * (t16 * t16);
    }
    const float shiftA[4] = {-2.2627417f, -4.1719303f, -6.0811183f, -7.9903066f};
    #pragma unroll
    for (int ii = 0; ii < 4; ++ii) {
        float x  = d12 + shiftA[ii];
        float f2 = __expf(-x * x);
        if (f2 < 1e-7f) continue;
        #pragma unroll
        for (int j = 0; j < 4; ++j) {
            float v = f2 * fac1[j];
            if (v > 1e-8f) unsafeAtomicAdd(base + ii * 4 + j, v);
        }
    }
}

extern "C" void kernel_launch(void* const* d_in, const int* in_sizes, int n_in,
                              void* d_out, int out_size, void* d_ws, size_t ws_size,
                              hipStream_t stream)
{
    const int*   species = (const int*)  d_in[0];
    const float* rad_d   = (const float*)d_in[1];
    const float* rad_sw  = (const float*)d_in[2];
    const int*   esrc    = (const int*)  d_in[3];
    const int*   edst    = (const int*)  d_in[4];
    const float* ang_d   = (const float*)d_in[5];
    const float* ang_sw  = (const float*)d_in[6];
    const float* angles  = (const float*)d_in[7];
    const int*   cat     = (const int*)  d_in[8];
    const int*   asrc    = (const int*)  d_in[9];
    const int*   adst    = (const int*)  d_in[10];
    const int*   aed     = (const int*)  d_in[11];
    float* out = (float*)d_out;

    const int N  = in_sizes[0];
    const int ER = in_sizes[1];
    const int EA = in_sizes[5];
    const int P  = in_sizes[7];

    const int NB  = (N + kABUCK - 1) / kABUCK;                 // atom bins
    const int chR = (((ER + kNBR - 1) / kNBR) + 3) & ~3;       // mult-of-4 chunk
    const int chA = (((P  + kNBA - 1) / kNBA) + 3) & ~3;
    const int prepB = (EA + 1023) / 1024;

    // workspace layout
    char* w = (char*)d_ws;
    size_t pos = 0;
    auto take = [&](size_t nbytes) {
        size_t cur = pos;
        pos = (pos + nbytes + 255) & ~(size_t)255;
        return cur;
    };
    size_t ea_o   = take((size_t)EA * 2);                          // packed eaq (ushort)
    size_t rrec_o = take((size_t)kNBR * chR * 4);
    size_t arec_o = take((size_t)kNBA * chA * 8);
    size_t ort_o  = take((size_t)(kMaxBins + 1) * kNBR * 4);       // transposed
    size_t oat_o  = take((size_t)(kMaxBins + 1) * kNBA * 4);       // transposed
    const size_t need = pos;

    const bool sorted_ok = (ws_size >= need) && (NB <= kMaxBins) &&
                           (chR <= kSCap) && (chA <= kSCap) &&
                           ((P & 3) == 0) && ((ER & 3) == 0);

    if (sorted_ok) {
        unsigned short* eaq = (unsigned short*)(w + ea_o);
        unsigned* rrec  = (unsigned*)(w + rrec_o);
        uint2*    arec  = (uint2*)(w + arec_o);
        int*      offRT = (int*)(w + ort_o);
        int*      offAT = (int*)(w + oat_o);

        fused1<<<kNBR + prepB, 1024, 0, stream>>>(rad_d, rad_sw, esrc, edst, species,
                                                  rrec, offRT, ER, chR,
                                                  ang_d, ang_sw, aed, eaq, EA);
        fused2<<<kNBA + NB, 1024, 0, stream>>>(angles, cat, asrc, adst, eaq,
                                               arec, offAT, P, chA,
                                               rrec, offRT, chR, out, N);
        acc_ang<<<NB, 1024, 0, stream>>>(arec, offAT, chA, out, N);
    } else {
        hipMemsetAsync(d_out, 0, (size_t)out_size * sizeof(float), stream);
        radial_kernel<<<(ER + 255) / 256, 256, 0, stream>>>(rad_d, rad_sw, esrc, edst, species, out, ER);
        angular_fallback<<<(P + 255) / 256, 256, 0, stream>>>(angles, cat, asrc, adst,
                                                              ang_d, ang_sw, aed, species, out, P);
    }
}